// Round 13
// baseline (997.078 us; speedup 1.0000x reference)
//
#include <hip/hip_runtime.h>
#include <math.h>

// Exactness: the FPS argmax chain and the knn/ball-query comparisons must be
// bitwise identical to the numpy reference. Disable FMA contraction globally;
// use explicit fmaf() where fusion is wanted (non-comparison math).
#pragma clang fp contract(off)

typedef float v2f __attribute__((ext_vector_type(2)));

// ---------------------------------------------------------------------------
// prep: point norms (exact ((x*x+y*y)+z*z) order) + weight transposes
// ---------------------------------------------------------------------------
__global__ __launch_bounds__(256) void prep_kernel(
    const float* __restrict__ xyz, const float* __restrict__ w0,
    const float* __restrict__ w1, const float* __restrict__ w2,
    float* __restrict__ norms, float* __restrict__ W0T,
    float* __restrict__ W1T, float* __restrict__ W2c)
{
    int t = blockIdx.x * 256 + threadIdx.x;
    if (t < 16384) {
        float x = xyz[t*3+0], y = xyz[t*3+1], z = xyz[t*3+2];
        norms[t] = (x*x + y*y) + z*z;          // matches np.sum(a*a,-1) order
        int c = t >> 7, k = t & 127;
        W1T[c*128 + k] = w1[k*128 + c];
    }
    if (t < 2432) { int c = t / 19, i = t - c*19; W0T[t] = w0[i*128 + c]; }
    if (t < 128)  { W2c[t] = w2[t*256]; }
}

// ---------------------------------------------------------------------------
// DPP helpers (validated bit-exact rounds 2-12): 0xB1=xor1, 0x4E=xor2,
// 0x141=row_half_mirror (xor4 once quad-uniform), 0x140=row_mirror (xor8 once
// 8-uniform) -> 16-lane-uniform. 0x142/0x143=row_bcast15/31 complete a
// 64-lane max/min (idempotent-safe; lane 63 holds the result).
// ---------------------------------------------------------------------------
template<int CTRL>
__device__ __forceinline__ unsigned long long dpp_u64(unsigned long long k) {
    int lo = (int)(unsigned int)k;
    int hi = (int)(unsigned int)(k >> 32);
    int plo = __builtin_amdgcn_update_dpp(lo, lo, CTRL, 0xF, 0xF, false);
    int phi = __builtin_amdgcn_update_dpp(hi, hi, CTRL, 0xF, 0xF, false);
    return ((unsigned long long)(unsigned int)phi << 32) | (unsigned int)plo;
}
template<int CTRL>
__device__ __forceinline__ unsigned long long max_u64_dpp(unsigned long long k) {
    unsigned long long p = dpp_u64<CTRL>(k);
    return p > k ? p : k;
}
template<int CTRL>
__device__ __forceinline__ unsigned long long min_u64_dpp(unsigned long long k) {
    unsigned long long p = dpp_u64<CTRL>(k);
    return p < k ? p : k;
}
__device__ __forceinline__ unsigned long long max_u64(unsigned long long a,
                                                      unsigned long long b) {
    return a > b ? a : b;
}

// ---------------------------------------------------------------------------
// fused FPS + KDE — round-12 structure (measured 643us) with ONE change:
// the 7-step serial local scan is replaced by a 7-node u64-max TREE (depth 3).
// Key_k = (bits(md2_k)<<32) | ~p_k, where ~p_k is loop-invariant (precomputed
// ip[8]): keys assemble with zero ALU. Max over the same unique keys ==
// (max d, tie -> min p) == numpy argmax — semantics identical to rounds 2-12,
// only the reduction tree shape changed. Then the proven 2-level exchange:
// 4-step DPP max -> 16-lane-uniform, 32 LDS slots, single barrier, one
// aligned ds_read_b128 (2 slots/lane), pairwise + 4-step DPP max.
// ---------------------------------------------------------------------------
__global__ __launch_bounds__(512) void fps_kde_kernel(
    const float* __restrict__ xyz, const float* __restrict__ norms,
    float* __restrict__ new_xyz, float* __restrict__ invden)
{
    __shared__ float4 pts[4096];                 // 64KB
    __shared__ float  nxb[3072];                 // 12KB FPS output staging
    __shared__ __attribute__((aligned(16))) unsigned long long swk[2][32];
    int tid = threadIdx.x;

    if (blockIdx.x < 4) {
        // ------------------------------ FPS ------------------------------
        int b = blockIdx.x;
        const float* Xb = xyz + b*12288;
        for (int t = tid; t < 4096; t += 512)
            pts[t] = make_float4(Xb[t*3+0], Xb[t*3+1], Xb[t*3+2], 0.0f);
        __syncthreads();
        float4 P[8];
#pragma unroll
        for (int k = 0; k < 8; ++k) P[k] = pts[k*512 + tid];
        v2f Xp[4], Yp[4], Zp[4], md2[4];
#pragma unroll
        for (int k = 0; k < 4; ++k) {
            Xp[k].x = P[k].x;  Xp[k].y = P[k+4].x;
            Yp[k].x = P[k].y;  Yp[k].y = P[k+4].y;
            Zp[k].x = P[k].z;  Zp[k].y = P[k+4].z;
            md2[k].x = INFINITY; md2[k].y = INFINITY;
        }
        // loop-invariant inverted indices: slot k<4 -> md2[k].x (p=k*512+tid),
        // slot k>=4 -> md2[k-4].y (p=k*512+tid)
        unsigned ip[8];
#pragma unroll
        for (int k = 0; k < 8; ++k) ip[k] = ~((unsigned)(k*512 + tid));
        float cx = pts[0].x, cy = pts[0].y, cz = pts[0].z;
        if (tid == 0) { nxb[0] = cx; nxb[1] = cy; nxb[2] = cz; }
        int buf = 0;
        for (int it = 1; it < 1024; ++it) {
            v2f cx2, cy2, cz2;
            cx2.x = cx; cx2.y = cx;
            cy2.x = cy; cy2.y = cy;
            cz2.x = cz; cz2.y = cz;
#pragma unroll
            for (int k = 0; k < 4; ++k) {
                v2f dx = Xp[k] - cx2, dy = Yp[k] - cy2, dz = Zp[k] - cz2;
                v2f dd = (dx*dx + dy*dy) + dz*dz;   // unfused (contract off)
                md2[k].x = fminf(md2[k].x, dd.x);
                md2[k].y = fminf(md2[k].y, dd.y);
            }
            // 8 keys (zero-ALU assembly: hi=float bits, lo=precomputed ip)
            unsigned long long k0 =
                ((unsigned long long)__float_as_uint(md2[0].x) << 32) | ip[0];
            unsigned long long k1 =
                ((unsigned long long)__float_as_uint(md2[1].x) << 32) | ip[1];
            unsigned long long k2 =
                ((unsigned long long)__float_as_uint(md2[2].x) << 32) | ip[2];
            unsigned long long k3 =
                ((unsigned long long)__float_as_uint(md2[3].x) << 32) | ip[3];
            unsigned long long k4 =
                ((unsigned long long)__float_as_uint(md2[0].y) << 32) | ip[4];
            unsigned long long k5 =
                ((unsigned long long)__float_as_uint(md2[1].y) << 32) | ip[5];
            unsigned long long k6 =
                ((unsigned long long)__float_as_uint(md2[2].y) << 32) | ip[6];
            unsigned long long k7 =
                ((unsigned long long)__float_as_uint(md2[3].y) << 32) | ip[7];
            // 7-node max tree, depth 3
            unsigned long long t01 = max_u64(k0, k1);
            unsigned long long t23 = max_u64(k2, k3);
            unsigned long long t45 = max_u64(k4, k5);
            unsigned long long t67 = max_u64(k6, k7);
            unsigned long long t03 = max_u64(t01, t23);
            unsigned long long t47 = max_u64(t45, t67);
            unsigned long long key = max_u64(t03, t47);
            // 4-step DPP u64 max -> uniform within each 16-lane group
            key = max_u64_dpp<0xB1>(key);
            key = max_u64_dpp<0x4E>(key);
            key = max_u64_dpp<0x141>(key);
            key = max_u64_dpp<0x140>(key);
            if ((tid & 15) == 0) swk[buf][tid >> 4] = key;   // 32 slots
            __syncthreads();                 // single barrier (dbuf'd slots)
            // each lane: 2 slots via one aligned b128 read, pairwise max,
            // then 4-step DPP max -> global winner in every lane
            uint4 w4 = *((const uint4*)&swk[buf][(tid & 15) << 1]);
            unsigned long long kA = ((unsigned long long)w4.y << 32) | w4.x;
            unsigned long long kB = ((unsigned long long)w4.w << 32) | w4.z;
            unsigned long long kk = kA > kB ? kA : kB;
            kk = max_u64_dpp<0xB1>(kk);
            kk = max_u64_dpp<0x4E>(kk);
            kk = max_u64_dpp<0x141>(kk);
            kk = max_u64_dpp<0x140>(kk);
            int fp = (int)(~(unsigned int)kk);
            float4 c = pts[fp];              // broadcast read
            cx = c.x; cy = c.y; cz = c.z;
            if (tid == 0) { nxb[it*3+0] = cx; nxb[it*3+1] = cy; nxb[it*3+2] = cz; }
            buf ^= 1;
        }
        __syncthreads();
        float* NX = new_xyz + b*3072;
        for (int t = tid; t < 3072; t += 512) NX[t] = nxb[t];
    } else {
        // ------------------------------ KDE ------------------------------
        // In-ball count ~17 << KDE_K=128, so the reference's top-128 +
        // padding + correction reduces exactly to the mean of mvn over all
        // in-ball neighbors. Membership test uses the pdist2 expansion
        // formula (unfused) to match the reference set bitwise.
        int idx = blockIdx.x - 4;
        int b = idx >> 9;                    // 512 blocks per batch
        int wave = tid >> 6, lane = tid & 63;
        int i_local = ((idx & 511) << 3) + wave;
        const float* Xb = xyz + b*12288;
        const float* Nb = norms + b*4096;
        for (int t = tid; t < 4096; t += 512)
            pts[t] = make_float4(Xb[t*3+0], Xb[t*3+1], Xb[t*3+2], Nb[t]);
        __syncthreads();
        float4 c = pts[i_local];
        const float Rv    = sqrtf(0.05f);
        const float inv_s = 1.0f / (Rv*Rv);
        const float K1    = -3.0f*logf(Rv) - 1.5f*logf(2.0f*3.1415926f);
        float csum = 0.0f; int cnt = 0;
        for (int j = lane; j < 4096; j += 64) {
            float4 q = pts[j];
            float dot = (c.x*q.x + c.y*q.y) + c.z*q.z;
            float t2 = 2.0f * dot;
            float d2 = (c.w + q.w) - t2;
            if (d2 < 0.01f) {                // 0.01f == float32(0.1*0.1)
                float gx = q.x - c.x, gy = q.y - c.y, gz = q.z - c.z;
                float dd = (gx*gx + gy*gy) + gz*gz;
                csum += expf(-0.5f * (dd * inv_s) + K1);
                cnt  += 1;
            }
        }
#pragma unroll
        for (int m = 1; m < 64; m <<= 1) {
            csum += __shfl_xor(csum, m, 64);
            cnt  += __shfl_xor(cnt,  m, 64);
        }
        if (lane == 0) {
            float den = csum / (float)cnt;
            invden[b*4096 + i_local] = 1.0f / den;
        }
    }
}

// ---------------------------------------------------------------------------
// KNN (round-7/12 version, measured): one wave per query, BARRIER-FREE — each
// wave owns its LDS slice, holds sign-transformed u32 ords (unsigned order ==
// float order; excluded = 0xFFFFFFFF). 32 rounds of lex-min (ord, j) via DPP
// u64-min == stable top_k. Winners buffered in LDS; one global burst at end.
// ---------------------------------------------------------------------------
__global__ __launch_bounds__(256) void knn_kernel(
    const float* __restrict__ xyz, const float* __restrict__ norms,
    const float* __restrict__ new_xyz, int* __restrict__ knn_idx)
{
    __shared__ unsigned sd2[4*4096];  // 64KB
    __shared__ int sIdx[4*32];
    int wave = threadIdx.x >> 6, lane = threadIdx.x & 63;
    int qg = blockIdx.x*4 + wave;  // global query id = b*1024 + q
    int b = qg >> 10;
    const float* Q = new_xyz + qg*3;
    float qx = Q[0], qy = Q[1], qz = Q[2];
    float nq = (qx*qx + qy*qy) + qz*qz;
    const float* Xb = xyz + b*12288;
    const float* Nb = norms + b*4096;
    unsigned* d2w = sd2 + wave*4096;
    for (int j = lane; j < 4096; j += 64) {
        float x = Xb[j*3+0], y = Xb[j*3+1], z = Xb[j*3+2];
        float dot = (qx*x + qy*y) + qz*z;
        float t2 = 2.0f*dot;
        float d = (nq + Nb[j]) - t2;
        unsigned u = __float_as_uint(d);
        unsigned m = ((unsigned)((int)u >> 31)) | 0x80000000u;
        d2w[j] = u ^ m;
    }
    for (int r = 0; r < 32; ++r) {
        unsigned best = 0xFFFFFFFFu; int bj = 0;
#pragma unroll
        for (int t = 0; t < 16; ++t) {
            int jb = t*256 + lane*4;
            uint4 v = *((const uint4*)(d2w + jb));
            if (v.x < best) { best = v.x; bj = jb;   }
            if (v.y < best) { best = v.y; bj = jb+1; }
            if (v.z < best) { best = v.z; bj = jb+2; }
            if (v.w < best) { best = v.w; bj = jb+3; }
        }
        unsigned long long key = ((unsigned long long)best << 32) | (unsigned)bj;
        key = min_u64_dpp<0xB1>(key);
        key = min_u64_dpp<0x4E>(key);
        key = min_u64_dpp<0x141>(key);
        key = min_u64_dpp<0x140>(key);
        key = min_u64_dpp<0x142>(key);
        key = min_u64_dpp<0x143>(key);   // lane 63 holds wave min
        int jwin = __builtin_amdgcn_readlane((int)(unsigned)key, 63);
        if (lane == 0) { sIdx[wave*32 + r] = jwin; d2w[jwin] = 0xFFFFFFFFu; }
    }
    if (lane < 32) knn_idx[qg*32 + lane] = sIdx[wave*32 + lane];
}

// ---------------------------------------------------------------------------
// Grouped MLP + fused final: thread per (b,p,k) row; chain 19->128->128->1
// (only channel 0 of mlp2 is consumed). The k-sum butterfly is an all-reduce,
// so every lane of a 32-half holds all 32 pw[w] totals in registers; each
// half-wave then writes its point's 256 outputs directly (8/lane, coalesced,
// same ascending-w fmaf order as the old final_kernel -> bitwise identical).
// Removes the final_kernel launch and the 2MB ptsw round-trip.
// ---------------------------------------------------------------------------
__global__ __launch_bounds__(256, 2) void group_mlp_kernel(
    const float* __restrict__ xyz, const float* __restrict__ feat,
    const float* __restrict__ new_xyz, const int* __restrict__ knn_idx,
    const float* __restrict__ invden,
    const float* __restrict__ W0T, const float* __restrict__ W1T,
    const float* __restrict__ W2c, const float* __restrict__ wwn,
    const float* __restrict__ wnl0, const float* __restrict__ wnl1,
    const float* __restrict__ wnp, float* __restrict__ out2)
{
    int row = blockIdx.x*256 + threadIdx.x;   // 131072 rows
    int k  = row & 31;
    int pg = row >> 5;                         // b*1024+p
    int b  = row >> 15;
    int j  = knn_idx[row];
    const float* Xb = xyz + b*12288;
    const float* Q  = new_xyz + pg*3;
    float in[19];
    in[0] = Xb[j*3+0] - Q[0];
    in[1] = Xb[j*3+1] - Q[1];
    in[2] = Xb[j*3+2] - Q[2];
    const float4* F = (const float4*)(feat + (size_t)(b*4096 + j)*16);
    float4 f0 = F[0], f1 = F[1], f2 = F[2], f3 = F[3];
    in[3]=f0.x; in[4]=f0.y; in[5]=f0.z; in[6]=f0.w;
    in[7]=f1.x; in[8]=f1.y; in[9]=f1.z; in[10]=f1.w;
    in[11]=f2.x; in[12]=f2.y; in[13]=f2.z; in[14]=f2.w;
    in[15]=f3.x; in[16]=f3.y; in[17]=f3.z; in[18]=f3.w;

    // density scale: gd / max_k(gd), then 1->16->1 relu MLP
    float gd = invden[b*4096 + j];
    float mx = gd;
#pragma unroll
    for (int m = 1; m < 32; m <<= 1) mx = fmaxf(mx, __shfl_xor(mx, m, 64));
    float dsc = gd / mx;
    float sacc = 0.0f;
#pragma unroll
    for (int t = 0; t < 16; ++t)
        sacc = fmaf(fmaxf(dsc * wnl0[t], 0.0f), wnl1[t], sacc);
    float ds = fmaxf(sacc, 0.0f);

    // L0: 19 -> 128 (fully unrolled so h1 stays in registers)
    float h1[128];
#pragma unroll
    for (int c = 0; c < 128; ++c) {
        const float* w = W0T + c*19;
        float a = in[0]*w[0];
#pragma unroll
        for (int i = 1; i < 19; ++i) a = fmaf(in[i], w[i], a);
        h1[c] = fmaxf(a, 0.0f);
    }
    // L1 + L2(col 0): dynamic outer loop, unrolled inner with 4 accumulators
    float acc0 = 0.0f;
    for (int c2 = 0; c2 < 128; ++c2) {
        const float* w = W1T + c2*128;
        float a0 = 0.0f, a1 = 0.0f, a2 = 0.0f, a3 = 0.0f;
#pragma unroll
        for (int kk = 0; kk < 128; kk += 4) {
            a0 = fmaf(h1[kk+0], w[kk+0], a0);
            a1 = fmaf(h1[kk+1], w[kk+1], a1);
            a2 = fmaf(h1[kk+2], w[kk+2], a2);
            a3 = fmaf(h1[kk+3], w[kk+3], a3);
        }
        float a = (a0+a1) + (a2+a3);
        acc0 = fmaf(fmaxf(a, 0.0f), W2c[c2], acc0);
    }
    float h0 = fmaxf(acc0, 0.0f);
    float s = h0 * ds;

    // weight net (3->32) + k-sum all-reduce (butterfly over each 32-half):
    // after the butterfly EVERY lane holds the total, kept in pw[32] regs.
    float gx = in[0], gy = in[1], gz = in[2];
    float pw[32];
#pragma unroll
    for (int w = 0; w < 32; ++w) {
        float a = gx * wwn[w];
        a = fmaf(gy, wwn[32+w], a);
        a = fmaf(gz, wwn[64+w], a);
        float part = s * fmaxf(a, 0.0f);
#pragma unroll
        for (int m = 1; m < 32; m <<= 1) part += __shfl_xor(part, m, 64);
        pw[w] = part;
    }

    // fused final: out[pg, f] = relu( sum_w pw[w] * wnp[w,f] ),
    // f = o*32 + k (lanes of a half-wave consecutive -> coalesced)
    float* outq = out2 + (size_t)pg*256;
#pragma unroll
    for (int o = 0; o < 8; ++o) {
        int f = o*32 + k;
        float a = 0.0f;
#pragma unroll
        for (int w = 0; w < 32; ++w) a = fmaf(pw[w], wnp[w*256+f], a);
        outq[f] = fmaxf(a, 0.0f);
    }
}

// ---------------------------------------------------------------------------
extern "C" void kernel_launch(void* const* d_in, const int* in_sizes, int n_in,
                              void* d_out, int out_size, void* d_ws, size_t ws_size,
                              hipStream_t stream) {
    const float* xyz  = (const float*)d_in[0];
    const float* feat = (const float*)d_in[1];
    const float* w0   = (const float*)d_in[2];
    const float* w1   = (const float*)d_in[3];
    const float* w2   = (const float*)d_in[4];
    const float* wwn  = (const float*)d_in[5];
    const float* wnl0 = (const float*)d_in[6];
    const float* wnl1 = (const float*)d_in[7];
    const float* wnp  = (const float*)d_in[8];

    float* out_all  = (float*)d_out;
    float* new_xyz  = out_all;            // 4*1024*3 = 12288 floats
    float* out2     = out_all + 12288;    // 4*1024*256 floats

    char* ws = (char*)d_ws;
    float* norms  = (float*)(ws + 0);        // 16384 f  (64KB)
    float* invden = (float*)(ws + 65536);    // 16384 f  (64KB)
    int*   knn    = (int*)  (ws + 131072);   // 131072 i (512KB)
    float* W0T    = (float*)(ws + 655360);   // 2432 f
    float* W1T    = (float*)(ws + 665088);   // 16384 f
    float* W2c    = (float*)(ws + 730624);   // 128 f

    prep_kernel<<<64, 256, 0, stream>>>(xyz, w0, w1, w2, norms, W0T, W1T, W2c);
    fps_kde_kernel<<<2052, 512, 0, stream>>>(xyz, norms, new_xyz, invden);
    knn_kernel<<<1024, 256, 0, stream>>>(xyz, norms, new_xyz, knn);
    group_mlp_kernel<<<512, 256, 0, stream>>>(xyz, feat, new_xyz, knn, invden,
                                              W0T, W1T, W2c, wwn, wnl0, wnl1,
                                              wnp, out2);
}

// Round 14
// 947.088 us; speedup vs baseline: 1.0528x; 1.0528x over previous
//
#include <hip/hip_runtime.h>
#include <math.h>

// Exactness: the FPS argmax chain and the knn/ball-query comparisons must be
// bitwise identical to the numpy reference. Disable FMA contraction globally;
// use explicit fmaf() where fusion is wanted (non-comparison math).
#pragma clang fp contract(off)

typedef float v2f __attribute__((ext_vector_type(2)));

// ---------------------------------------------------------------------------
// prep: point norms (exact ((x*x+y*y)+z*z) order) + weight transposes
// ---------------------------------------------------------------------------
__global__ __launch_bounds__(256) void prep_kernel(
    const float* __restrict__ xyz, const float* __restrict__ w0,
    const float* __restrict__ w1, const float* __restrict__ w2,
    float* __restrict__ norms, float* __restrict__ W0T,
    float* __restrict__ W1T, float* __restrict__ W2c)
{
    int t = blockIdx.x * 256 + threadIdx.x;
    if (t < 16384) {
        float x = xyz[t*3+0], y = xyz[t*3+1], z = xyz[t*3+2];
        norms[t] = (x*x + y*y) + z*z;          // matches np.sum(a*a,-1) order
        int c = t >> 7, k = t & 127;
        W1T[c*128 + k] = w1[k*128 + c];
    }
    if (t < 2432) { int c = t / 19, i = t - c*19; W0T[t] = w0[i*128 + c]; }
    if (t < 128)  { W2c[t] = w2[t*256]; }
}

// ---------------------------------------------------------------------------
// DPP helpers (validated bit-exact rounds 2-13): 0xB1=xor1, 0x4E=xor2,
// 0x141=row_half_mirror (xor4 once quad-uniform), 0x140=row_mirror (xor8 once
// 8-uniform) -> 16-lane-uniform. 0x142/0x143=row_bcast15/31 complete a
// 64-lane max/min (idempotent-safe; lane 63 holds the result).
// ---------------------------------------------------------------------------
template<int CTRL>
__device__ __forceinline__ unsigned long long dpp_u64(unsigned long long k) {
    int lo = (int)(unsigned int)k;
    int hi = (int)(unsigned int)(k >> 32);
    int plo = __builtin_amdgcn_update_dpp(lo, lo, CTRL, 0xF, 0xF, false);
    int phi = __builtin_amdgcn_update_dpp(hi, hi, CTRL, 0xF, 0xF, false);
    return ((unsigned long long)(unsigned int)phi << 32) | (unsigned int)plo;
}
template<int CTRL>
__device__ __forceinline__ unsigned long long max_u64_dpp(unsigned long long k) {
    unsigned long long p = dpp_u64<CTRL>(k);
    return p > k ? p : k;
}
template<int CTRL>
__device__ __forceinline__ unsigned long long min_u64_dpp(unsigned long long k) {
    unsigned long long p = dpp_u64<CTRL>(k);
    return p < k ? p : k;
}
__device__ __forceinline__ unsigned long long max_u64(unsigned long long a,
                                                      unsigned long long b) {
    return a > b ? a : b;
}

// ---------------------------------------------------------------------------
// fused FPS + KDE — round-13 FPS (measured 634.6us, best of 14 variants).
// FPS: 7-node u64-max tree over 8 keys (hi = bits(md2), lo = loop-invariant
// precomputed ~p -> zero-ALU key assembly; max == (max d, tie -> min p) ==
// numpy argmax), then 4-step DPP max -> 16-lane-uniform, 32 LDS slots,
// single barrier (double-buffered), one aligned ds_read_b128 (2 slots/lane),
// pairwise + 4-step DPP max -> winner in all lanes. No VMEM in the loop.
// ---------------------------------------------------------------------------
__global__ __launch_bounds__(512) void fps_kde_kernel(
    const float* __restrict__ xyz, const float* __restrict__ norms,
    float* __restrict__ new_xyz, float* __restrict__ invden)
{
    __shared__ float4 pts[4096];                 // 64KB
    __shared__ float  nxb[3072];                 // 12KB FPS output staging
    __shared__ __attribute__((aligned(16))) unsigned long long swk[2][32];
    int tid = threadIdx.x;

    if (blockIdx.x < 4) {
        // ------------------------------ FPS ------------------------------
        int b = blockIdx.x;
        const float* Xb = xyz + b*12288;
        for (int t = tid; t < 4096; t += 512)
            pts[t] = make_float4(Xb[t*3+0], Xb[t*3+1], Xb[t*3+2], 0.0f);
        __syncthreads();
        float4 P[8];
#pragma unroll
        for (int k = 0; k < 8; ++k) P[k] = pts[k*512 + tid];
        v2f Xp[4], Yp[4], Zp[4], md2[4];
#pragma unroll
        for (int k = 0; k < 4; ++k) {
            Xp[k].x = P[k].x;  Xp[k].y = P[k+4].x;
            Yp[k].x = P[k].y;  Yp[k].y = P[k+4].y;
            Zp[k].x = P[k].z;  Zp[k].y = P[k+4].z;
            md2[k].x = INFINITY; md2[k].y = INFINITY;
        }
        // loop-invariant inverted indices: slot k<4 -> md2[k].x (p=k*512+tid),
        // slot k>=4 -> md2[k-4].y (p=k*512+tid)
        unsigned ip[8];
#pragma unroll
        for (int k = 0; k < 8; ++k) ip[k] = ~((unsigned)(k*512 + tid));
        float cx = pts[0].x, cy = pts[0].y, cz = pts[0].z;
        if (tid == 0) { nxb[0] = cx; nxb[1] = cy; nxb[2] = cz; }
        int buf = 0;
        for (int it = 1; it < 1024; ++it) {
            v2f cx2, cy2, cz2;
            cx2.x = cx; cx2.y = cx;
            cy2.x = cy; cy2.y = cy;
            cz2.x = cz; cz2.y = cz;
#pragma unroll
            for (int k = 0; k < 4; ++k) {
                v2f dx = Xp[k] - cx2, dy = Yp[k] - cy2, dz = Zp[k] - cz2;
                v2f dd = (dx*dx + dy*dy) + dz*dz;   // unfused (contract off)
                md2[k].x = fminf(md2[k].x, dd.x);
                md2[k].y = fminf(md2[k].y, dd.y);
            }
            // 8 keys (zero-ALU assembly: hi=float bits, lo=precomputed ip)
            unsigned long long k0 =
                ((unsigned long long)__float_as_uint(md2[0].x) << 32) | ip[0];
            unsigned long long k1 =
                ((unsigned long long)__float_as_uint(md2[1].x) << 32) | ip[1];
            unsigned long long k2 =
                ((unsigned long long)__float_as_uint(md2[2].x) << 32) | ip[2];
            unsigned long long k3 =
                ((unsigned long long)__float_as_uint(md2[3].x) << 32) | ip[3];
            unsigned long long k4 =
                ((unsigned long long)__float_as_uint(md2[0].y) << 32) | ip[4];
            unsigned long long k5 =
                ((unsigned long long)__float_as_uint(md2[1].y) << 32) | ip[5];
            unsigned long long k6 =
                ((unsigned long long)__float_as_uint(md2[2].y) << 32) | ip[6];
            unsigned long long k7 =
                ((unsigned long long)__float_as_uint(md2[3].y) << 32) | ip[7];
            // 7-node max tree, depth 3
            unsigned long long t01 = max_u64(k0, k1);
            unsigned long long t23 = max_u64(k2, k3);
            unsigned long long t45 = max_u64(k4, k5);
            unsigned long long t67 = max_u64(k6, k7);
            unsigned long long t03 = max_u64(t01, t23);
            unsigned long long t47 = max_u64(t45, t67);
            unsigned long long key = max_u64(t03, t47);
            // 4-step DPP u64 max -> uniform within each 16-lane group
            key = max_u64_dpp<0xB1>(key);
            key = max_u64_dpp<0x4E>(key);
            key = max_u64_dpp<0x141>(key);
            key = max_u64_dpp<0x140>(key);
            if ((tid & 15) == 0) swk[buf][tid >> 4] = key;   // 32 slots
            __syncthreads();                 // single barrier (dbuf'd slots)
            // each lane: 2 slots via one aligned b128 read, pairwise max,
            // then 4-step DPP max -> global winner in every lane
            uint4 w4 = *((const uint4*)&swk[buf][(tid & 15) << 1]);
            unsigned long long kA = ((unsigned long long)w4.y << 32) | w4.x;
            unsigned long long kB = ((unsigned long long)w4.w << 32) | w4.z;
            unsigned long long kk = kA > kB ? kA : kB;
            kk = max_u64_dpp<0xB1>(kk);
            kk = max_u64_dpp<0x4E>(kk);
            kk = max_u64_dpp<0x141>(kk);
            kk = max_u64_dpp<0x140>(kk);
            int fp = (int)(~(unsigned int)kk);
            float4 c = pts[fp];              // broadcast read
            cx = c.x; cy = c.y; cz = c.z;
            if (tid == 0) { nxb[it*3+0] = cx; nxb[it*3+1] = cy; nxb[it*3+2] = cz; }
            buf ^= 1;
        }
        __syncthreads();
        float* NX = new_xyz + b*3072;
        for (int t = tid; t < 3072; t += 512) NX[t] = nxb[t];
    } else {
        // ------------------------------ KDE ------------------------------
        // In-ball count ~17 << KDE_K=128, so the reference's top-128 +
        // padding + correction reduces exactly to the mean of mvn over all
        // in-ball neighbors. Membership test uses the pdist2 expansion
        // formula (unfused) to match the reference set bitwise.
        int idx = blockIdx.x - 4;
        int b = idx >> 9;                    // 512 blocks per batch
        int wave = tid >> 6, lane = tid & 63;
        int i_local = ((idx & 511) << 3) + wave;
        const float* Xb = xyz + b*12288;
        const float* Nb = norms + b*4096;
        for (int t = tid; t < 4096; t += 512)
            pts[t] = make_float4(Xb[t*3+0], Xb[t*3+1], Xb[t*3+2], Nb[t]);
        __syncthreads();
        float4 c = pts[i_local];
        const float Rv    = sqrtf(0.05f);
        const float inv_s = 1.0f / (Rv*Rv);
        const float K1    = -3.0f*logf(Rv) - 1.5f*logf(2.0f*3.1415926f);
        float csum = 0.0f; int cnt = 0;
        for (int j = lane; j < 4096; j += 64) {
            float4 q = pts[j];
            float dot = (c.x*q.x + c.y*q.y) + c.z*q.z;
            float t2 = 2.0f * dot;
            float d2 = (c.w + q.w) - t2;
            if (d2 < 0.01f) {                // 0.01f == float32(0.1*0.1)
                float gx = q.x - c.x, gy = q.y - c.y, gz = q.z - c.z;
                float dd = (gx*gx + gy*gy) + gz*gz;
                csum += expf(-0.5f * (dd * inv_s) + K1);
                cnt  += 1;
            }
        }
#pragma unroll
        for (int m = 1; m < 64; m <<= 1) {
            csum += __shfl_xor(csum, m, 64);
            cnt  += __shfl_xor(cnt,  m, 64);
        }
        if (lane == 0) {
            float den = csum / (float)cnt;
            invden[b*4096 + i_local] = 1.0f / den;
        }
    }
}

// ---------------------------------------------------------------------------
// KNN (round-7/12 version, measured): one wave per query, BARRIER-FREE — each
// wave owns its LDS slice, holds sign-transformed u32 ords (unsigned order ==
// float order; excluded = 0xFFFFFFFF). 32 rounds of lex-min (ord, j) via DPP
// u64-min == stable top_k. Winners buffered in LDS; one global burst at end.
// ---------------------------------------------------------------------------
__global__ __launch_bounds__(256) void knn_kernel(
    const float* __restrict__ xyz, const float* __restrict__ norms,
    const float* __restrict__ new_xyz, int* __restrict__ knn_idx)
{
    __shared__ unsigned sd2[4*4096];  // 64KB
    __shared__ int sIdx[4*32];
    int wave = threadIdx.x >> 6, lane = threadIdx.x & 63;
    int qg = blockIdx.x*4 + wave;  // global query id = b*1024 + q
    int b = qg >> 10;
    const float* Q = new_xyz + qg*3;
    float qx = Q[0], qy = Q[1], qz = Q[2];
    float nq = (qx*qx + qy*qy) + qz*qz;
    const float* Xb = xyz + b*12288;
    const float* Nb = norms + b*4096;
    unsigned* d2w = sd2 + wave*4096;
    for (int j = lane; j < 4096; j += 64) {
        float x = Xb[j*3+0], y = Xb[j*3+1], z = Xb[j*3+2];
        float dot = (qx*x + qy*y) + qz*z;
        float t2 = 2.0f*dot;
        float d = (nq + Nb[j]) - t2;
        unsigned u = __float_as_uint(d);
        unsigned m = ((unsigned)((int)u >> 31)) | 0x80000000u;
        d2w[j] = u ^ m;
    }
    for (int r = 0; r < 32; ++r) {
        unsigned best = 0xFFFFFFFFu; int bj = 0;
#pragma unroll
        for (int t = 0; t < 16; ++t) {
            int jb = t*256 + lane*4;
            uint4 v = *((const uint4*)(d2w + jb));
            if (v.x < best) { best = v.x; bj = jb;   }
            if (v.y < best) { best = v.y; bj = jb+1; }
            if (v.z < best) { best = v.z; bj = jb+2; }
            if (v.w < best) { best = v.w; bj = jb+3; }
        }
        unsigned long long key = ((unsigned long long)best << 32) | (unsigned)bj;
        key = min_u64_dpp<0xB1>(key);
        key = min_u64_dpp<0x4E>(key);
        key = min_u64_dpp<0x141>(key);
        key = min_u64_dpp<0x140>(key);
        key = min_u64_dpp<0x142>(key);
        key = min_u64_dpp<0x143>(key);   // lane 63 holds wave min
        int jwin = __builtin_amdgcn_readlane((int)(unsigned)key, 63);
        if (lane == 0) { sIdx[wave*32 + r] = jwin; d2w[jwin] = 0xFFFFFFFFu; }
    }
    if (lane < 32) knn_idx[qg*32 + lane] = sIdx[wave*32 + lane];
}

// ---------------------------------------------------------------------------
// Grouped MLP (round-12 version, measured): thread per (b,p,k) row. Only
// channel 0 of mlp2 is consumed (pts[:,:,0,:]) -> chain 19->128->128->1.
// k-sum written by k==0 lane to ptsw (keeps VGPR peak down — round 13's
// in-register pw[32] + fused final regressed ~49us via pressure/spills).
// ---------------------------------------------------------------------------
__global__ __launch_bounds__(256, 2) void group_mlp_kernel(
    const float* __restrict__ xyz, const float* __restrict__ feat,
    const float* __restrict__ new_xyz, const int* __restrict__ knn_idx,
    const float* __restrict__ invden,
    const float* __restrict__ W0T, const float* __restrict__ W1T,
    const float* __restrict__ W2c, const float* __restrict__ wwn,
    const float* __restrict__ wnl0, const float* __restrict__ wnl1,
    float* __restrict__ ptsw)
{
    int row = blockIdx.x*256 + threadIdx.x;   // 131072 rows
    int k  = row & 31;
    int pg = row >> 5;                         // b*1024+p
    int b  = row >> 15;
    int j  = knn_idx[row];
    const float* Xb = xyz + b*12288;
    const float* Q  = new_xyz + pg*3;
    float in[19];
    in[0] = Xb[j*3+0] - Q[0];
    in[1] = Xb[j*3+1] - Q[1];
    in[2] = Xb[j*3+2] - Q[2];
    const float4* F = (const float4*)(feat + (size_t)(b*4096 + j)*16);
    float4 f0 = F[0], f1 = F[1], f2 = F[2], f3 = F[3];
    in[3]=f0.x; in[4]=f0.y; in[5]=f0.z; in[6]=f0.w;
    in[7]=f1.x; in[8]=f1.y; in[9]=f1.z; in[10]=f1.w;
    in[11]=f2.x; in[12]=f2.y; in[13]=f2.z; in[14]=f2.w;
    in[15]=f3.x; in[16]=f3.y; in[17]=f3.z; in[18]=f3.w;

    // density scale: gd / max_k(gd), then 1->16->1 relu MLP
    float gd = invden[b*4096 + j];
    float mx = gd;
#pragma unroll
    for (int m = 1; m < 32; m <<= 1) mx = fmaxf(mx, __shfl_xor(mx, m, 64));
    float dsc = gd / mx;
    float sacc = 0.0f;
#pragma unroll
    for (int t = 0; t < 16; ++t)
        sacc = fmaf(fmaxf(dsc * wnl0[t], 0.0f), wnl1[t], sacc);
    float ds = fmaxf(sacc, 0.0f);

    // L0: 19 -> 128 (fully unrolled so h1 stays in registers)
    float h1[128];
#pragma unroll
    for (int c = 0; c < 128; ++c) {
        const float* w = W0T + c*19;
        float a = in[0]*w[0];
#pragma unroll
        for (int i = 1; i < 19; ++i) a = fmaf(in[i], w[i], a);
        h1[c] = fmaxf(a, 0.0f);
    }
    // L1 + L2(col 0): dynamic outer loop, unrolled inner with 4 accumulators
    float acc0 = 0.0f;
    for (int c2 = 0; c2 < 128; ++c2) {
        const float* w = W1T + c2*128;
        float a0 = 0.0f, a1 = 0.0f, a2 = 0.0f, a3 = 0.0f;
#pragma unroll
        for (int kk = 0; kk < 128; kk += 4) {
            a0 = fmaf(h1[kk+0], w[kk+0], a0);
            a1 = fmaf(h1[kk+1], w[kk+1], a1);
            a2 = fmaf(h1[kk+2], w[kk+2], a2);
            a3 = fmaf(h1[kk+3], w[kk+3], a3);
        }
        float a = (a0+a1) + (a2+a3);
        acc0 = fmaf(fmaxf(a, 0.0f), W2c[c2], acc0);
    }
    float h0 = fmaxf(acc0, 0.0f);
    float s = h0 * ds;

    // weight net (3->32) + reduce over k (32 lanes of half-wave)
    float gx = in[0], gy = in[1], gz = in[2];
    float* pw = ptsw + pg*32;
#pragma unroll
    for (int w = 0; w < 32; ++w) {
        float a = gx * wwn[w];
        a = fmaf(gy, wwn[32+w], a);
        a = fmaf(gz, wwn[64+w], a);
        float part = s * fmaxf(a, 0.0f);
#pragma unroll
        for (int m = 1; m < 32; m <<= 1) part += __shfl_xor(part, m, 64);
        if (k == 0) pw[w] = part;
    }
}

// ---------------------------------------------------------------------------
// final: out[b,p,f] = relu( sum_w ptsw[b,p,w] * w_np[w,f] )
// ---------------------------------------------------------------------------
__global__ __launch_bounds__(256) void final_kernel(
    const float* __restrict__ ptsw, const float* __restrict__ wnp,
    float* __restrict__ out)
{
    int pg = blockIdx.x;       // 4096 = b*1024+p
    int f  = threadIdx.x;      // 256
    const float* pw = ptsw + pg*32;
    float a = 0.0f;
#pragma unroll
    for (int w = 0; w < 32; ++w) a = fmaf(pw[w], wnp[w*256+f], a);
    out[pg*256 + f] = fmaxf(a, 0.0f);
}

// ---------------------------------------------------------------------------
extern "C" void kernel_launch(void* const* d_in, const int* in_sizes, int n_in,
                              void* d_out, int out_size, void* d_ws, size_t ws_size,
                              hipStream_t stream) {
    const float* xyz  = (const float*)d_in[0];
    const float* feat = (const float*)d_in[1];
    const float* w0   = (const float*)d_in[2];
    const float* w1   = (const float*)d_in[3];
    const float* w2   = (const float*)d_in[4];
    const float* wwn  = (const float*)d_in[5];
    const float* wnl0 = (const float*)d_in[6];
    const float* wnl1 = (const float*)d_in[7];
    const float* wnp  = (const float*)d_in[8];

    float* out_all  = (float*)d_out;
    float* new_xyz  = out_all;            // 4*1024*3 = 12288 floats
    float* out2     = out_all + 12288;    // 4*1024*256 floats

    char* ws = (char*)d_ws;
    float* norms  = (float*)(ws + 0);        // 16384 f  (64KB)
    float* invden = (float*)(ws + 65536);    // 16384 f  (64KB)
    int*   knn    = (int*)  (ws + 131072);   // 131072 i (512KB)
    float* ptsw   = (float*)(ws + 655360);   // 131072 f (512KB)
    float* W0T    = (float*)(ws + 1179648);  // 2432 f
    float* W1T    = (float*)(ws + 1189376);  // 16384 f
    float* W2c    = (float*)(ws + 1254912);  // 128 f

    prep_kernel<<<64, 256, 0, stream>>>(xyz, w0, w1, w2, norms, W0T, W1T, W2c);
    fps_kde_kernel<<<2052, 512, 0, stream>>>(xyz, norms, new_xyz, invden);
    knn_kernel<<<1024, 256, 0, stream>>>(xyz, norms, new_xyz, knn);
    group_mlp_kernel<<<512, 256, 0, stream>>>(xyz, feat, new_xyz, knn, invden,
                                              W0T, W1T, W2c, wwn, wnl0, wnl1, ptsw);
    final_kernel<<<4096, 256, 0, stream>>>(ptsw, wnp, out2);
}